// Round 11
// baseline (214.577 us; speedup 1.0000x reference)
//
#include <hip/hip_runtime.h>
#include <hip/hip_cooperative_groups.h>

namespace cg = cooperative_groups;

#define B_SZ   8
#define SEQ    2048
#define PSEQ   (SEQ+16)     // 16 zero pad rows before each batch
#define SDIM   1024
#define DIN    512
#define DOUT   512
#define KX     10
#define RTOT   (B_SZ*SEQ)   // 16384
#define LC     64
#define NC     (SEQ/LC)     // 32

typedef __attribute__((ext_vector_type(8))) short short8;
typedef __attribute__((ext_vector_type(4))) float f32x4;
typedef __attribute__((ext_vector_type(4))) unsigned short bfx4;

// ---- workspace layout (bytes). Xp has 64 slack rows for X-prefetch overread.
#define OFF_XP   0UL             // (B_SZ*PSEQ+64)*DIN*2 = 16,973,824
#define OFF_UB   16973824UL      // RTOT*SDIM*2 (bf16)   = 33,554,432
#define OFF_HS   50528256UL      // RTOT*SDIM*2 (bf16)   = 33,554,432
#define OFF_BT   84082688UL      // SDIM*DIN*2           = 1,048,576
#define OFF_CT   85131264UL      // DOUT*SDIM*2          = 1,048,576
#define OFF_MT   86179840UL      // KX*DOUT*DIN*2        = 5,242,880

__device__ __forceinline__ short f2bf(float f) {
  unsigned u = __builtin_bit_cast(unsigned, f);
  u += 0x7fffu + ((u >> 16) & 1u);   // RNE
  return (short)(u >> 16);
}
__device__ __forceinline__ float bf2f(unsigned short b) {
  return __builtin_bit_cast(float, (unsigned)b << 16);
}

#define GLOAD16(gp, lp) __builtin_amdgcn_global_load_lds( \
    (const __attribute__((address_space(1))) void*)(gp), \
    (__attribute__((address_space(3))) void*)(lp), 16, 0, 0)
#define WAITVM(n) asm volatile("s_waitcnt vmcnt(" #n ")" ::: "memory")
#define LGKM0()   do { asm volatile("s_waitcnt lgkmcnt(0)" ::: "memory"); \
                       __builtin_amdgcn_sched_barrier(0); } while (0)
#define SBAR() __builtin_amdgcn_s_barrier()

// ================= conversion / prep (pad fused) =================
__global__ void k_conv_x(const float* __restrict__ in, short* __restrict__ out) {
  const int NG = RTOT * (DIN / 8);
  const int NPAD = B_SZ * 16 * (DIN / 8);
  for (int g = blockIdx.x * 256 + threadIdx.x; g < NG + NPAD; g += 2048 * 256) {
    if (g < NG) {
      int r = g >> 6, c8 = g & 63;
      int b = r >> 11, t = r & 2047;
      const float4* p = reinterpret_cast<const float4*>(in) + (size_t)g * 2;
      float4 f0 = p[0], f1 = p[1];
      short8 o;
      o[0]=f2bf(f0.x); o[1]=f2bf(f0.y); o[2]=f2bf(f0.z); o[3]=f2bf(f0.w);
      o[4]=f2bf(f1.x); o[5]=f2bf(f1.y); o[6]=f2bf(f1.z); o[7]=f2bf(f1.w);
      *reinterpret_cast<short8*>(out + ((size_t)(b * PSEQ + 16 + t) * DIN + c8 * 8)) = o;
    } else {
      int idx = g - NG;
      int b = idx >> 10, rem = idx & 1023;
      int row16 = rem >> 6, c8 = rem & 63;
      const short8 z = {0,0,0,0,0,0,0,0};
      *reinterpret_cast<short8*>(out + ((size_t)(b * PSEQ + row16) * DIN + c8 * 8)) = z;
    }
  }
}

__global__ void k_transpose_bf16(const float* __restrict__ in, short* __restrict__ out,
                                 int rows, int cols) {
  __shared__ float t[32][33];
  int bx = blockIdx.x * 32, by = blockIdx.y * 32;
  int tx = threadIdx.x & 31, ty = threadIdx.x >> 5;
  #pragma unroll
  for (int j = 0; j < 32; j += 8)
    t[ty + j][tx] = in[(size_t)(by + ty + j) * cols + (bx + tx)];
  __syncthreads();
  #pragma unroll
  for (int j = 0; j < 32; j += 8)
    out[(size_t)(bx + ty + j) * rows + (by + tx)] = f2bf(t[tx][ty + j]);
}

__global__ void k_prep_M(const float* __restrict__ M, short* __restrict__ Mt) {
  int idx = blockIdx.x * 256 + threadIdx.x;
  if (idx >= DOUT * DIN) return;
  int o = idx / DIN, i = idx - o * DIN;
  const float* src = M + ((size_t)o * DIN + i) * KX;
  #pragma unroll
  for (int t = 0; t < KX; ++t)
    Mt[((size_t)t * DOUT + o) * DIN + i] = f2bf(src[t]);
}

// ================= merged cooperative scan =================
// 256 blocks (1/CU) x 256 thr. Block g owns chunk (b,c)=(g>>5,g&31).
// LDS holds the 64x1024 bf16 uB chunk (128 KB) for both scan passes.
__global__ void __launch_bounds__(256) k_scan_all(const short* __restrict__ uB,
                                                  const float* __restrict__ A,
                                                  const float* __restrict__ h0,
                                                  float* __restrict__ E,
                                                  float* __restrict__ Sb,
                                                  short* __restrict__ hs) {
  __shared__ __attribute__((aligned(16))) short chunk[LC * SDIM];  // 128 KB
  cg::grid_group grid = cg::this_grid();
  int g = blockIdx.x, tid = threadIdx.x;
  int b = g >> 5, c = g & 31;
  const short* src = uB + ((size_t)b * SEQ + (size_t)c * LC) * SDIM;

  #pragma unroll
  for (int i = 0; i < 32; ++i) {
    int e8 = i * 256 + tid;                     // 16B-group index
    GLOAD16(src + e8 * 8, chunk + e8 * 8);
  }
  WAITVM(0);
  SBAR();

  // pass 1: zero-state chunk scan -> E[g]
  int s0 = tid * 4;
  float a0 = A[s0], a1 = A[s0+1], a2 = A[s0+2], a3 = A[s0+3];
  {
    float e0 = 0.f, e1 = 0.f, e2 = 0.f, e3 = 0.f;
    for (int t = 0; t < LC; ++t) {
      bfx4 v = *reinterpret_cast<const bfx4*>(chunk + t * SDIM + s0);
      e0 = fmaf(a0, e0, bf2f(v[0]));
      e1 = fmaf(a1, e1, bf2f(v[1]));
      e2 = fmaf(a2, e2, bf2f(v[2]));
      e3 = fmaf(a3, e3, bf2f(v[3]));
    }
    float4 ev = { e0, e1, e2, e3 };
    *reinterpret_cast<float4*>(E + (size_t)g * SDIM + s0) = ev;
  }
  grid.sync();

  // pass 2: chunk-boundary recurrence (blocks 0..31; 8192 (b,s) chains)
  if (g < 32) {
    int bb = g >> 2;
    int s = ((g & 3) << 8) + tid;
    float a = A[s], ap = a;
    #pragma unroll
    for (int q = 0; q < 6; ++q) ap *= ap;       // a^64
    float S = h0[s];
    for (int c2 = 0; c2 < NC; ++c2) {
      size_t idx = ((size_t)bb * NC + c2) * SDIM + s;
      Sb[idx] = S;
      S = fmaf(ap, S, E[idx]);
    }
  }
  grid.sync();

  // pass 3: seeded rescan from LDS -> hs (bf16)
  {
    float4 sv = *reinterpret_cast<const float4*>(Sb + (size_t)g * SDIM + s0);
    float h0_ = sv.x, h1_ = sv.y, h2_ = sv.z, h3_ = sv.w;
    short* dst = hs + ((size_t)b * SEQ + (size_t)c * LC) * SDIM + s0;
    for (int t = 0; t < LC; ++t) {
      bfx4 v = *reinterpret_cast<const bfx4*>(chunk + t * SDIM + s0);
      h0_ = fmaf(a0, h0_, bf2f(v[0]));
      h1_ = fmaf(a1, h1_, bf2f(v[1]));
      h2_ = fmaf(a2, h2_, bf2f(v[2]));
      h3_ = fmaf(a3, h3_, bf2f(v[3]));
      bfx4 o;
      o[0] = (unsigned short)f2bf(h0_);
      o[1] = (unsigned short)f2bf(h1_);
      o[2] = (unsigned short)f2bf(h2_);
      o[3] = (unsigned short)f2bf(h3_);
      *reinterpret_cast<bfx4*>(dst + (size_t)t * SDIM) = o;
    }
  }
}

// ================= GEMM1: 128x128, 4 waves, dbuf + counted vmcnt (proven) ====
__device__ __forceinline__ void stage128(const short* __restrict__ g, int ld,
                                         short* l, int tid) {
  int rsub = tid >> 3;
  int slot = (tid & 7) ^ (rsub & 7);
  #pragma unroll
  for (int i = 0; i < 4; ++i) {
    int row = i * 32 + rsub;
    GLOAD16(g + (size_t)row * ld + slot * 8, l + row * 64 + (tid & 7) * 8);
  }
}

__device__ __forceinline__ void mfma_tile(const short* lA, int aoff, const short* lB,
                                          int lane, int wm, int wn, f32x4 acc[4][4]) {
  int lr = lane & 15;
  int h  = lane >> 4;
  #pragma unroll
  for (int kk = 0; kk < 2; ++kk) {
    int kslot = kk * 4 + h;
    short8 af[4], bfr[4];
    #pragma unroll
    for (int mi = 0; mi < 4; ++mi) {
      int row = aoff + wm * 64 + mi * 16 + lr;
      af[mi] = *reinterpret_cast<const short8*>(lA + row * 64 + ((kslot ^ (row & 7)) << 3));
    }
    #pragma unroll
    for (int ni = 0; ni < 4; ++ni) {
      int row = wn * 64 + ni * 16 + lr;
      bfr[ni] = *reinterpret_cast<const short8*>(lB + row * 64 + ((kslot ^ (row & 7)) << 3));
    }
    __builtin_amdgcn_s_setprio(1);
    #pragma unroll
    for (int mi = 0; mi < 4; ++mi)
      #pragma unroll
      for (int ni = 0; ni < 4; ++ni)
        acc[mi][ni] = __builtin_amdgcn_mfma_f32_16x16x32_bf16(af[mi], bfr[ni], acc[mi][ni], 0, 0, 0);
    __builtin_amdgcn_s_setprio(0);
  }
}

__global__ __launch_bounds__(256) void k_gemm_uB(const short* __restrict__ Xp,
                                                 const short* __restrict__ Bt,
                                                 short* __restrict__ uB) {
  __shared__ __attribute__((aligned(16))) short lds[32768];
  short* A0 = lds;         short* B0 = lds + 8192;
  short* A1 = lds + 16384; short* B1 = lds + 24576;
  int tid = threadIdx.x, lane = tid & 63, w = tid >> 6, wm = w >> 1, wn = w & 1;
  long r0 = (long)blockIdx.x * 128;
  int  c0 = blockIdx.y * 128;
  int  b  = (int)(r0 >> 11);
  const short* Abase = Xp + (size_t)(r0 + 16 * (b + 1)) * DIN;
  const short* Bbase = Bt + (size_t)c0 * DIN;
  const f32x4 z4 = {0.f, 0.f, 0.f, 0.f};
  f32x4 acc[4][4];
  #pragma unroll
  for (int mi = 0; mi < 4; ++mi)
    #pragma unroll
    for (int ni = 0; ni < 4; ++ni) acc[mi][ni] = z4;

  stage128(Abase, DIN, A0, tid);      stage128(Bbase, DIN, B0, tid);
  stage128(Abase + 64, DIN, A1, tid); stage128(Bbase + 64, DIN, B1, tid);
  WAITVM(8);
  SBAR();
  for (int kt = 0; kt < 8; ++kt) {
    const short* a  = (kt & 1) ? A1 : A0;
    const short* bb = (kt & 1) ? B1 : B0;
    mfma_tile(a, 0, bb, lane, wm, wn, acc);
    SBAR();
    if (kt + 2 < 8) {
      short* ad = (kt & 1) ? A1 : A0;
      short* bd = (kt & 1) ? B1 : B0;
      stage128(Abase + (kt + 2) * 64, DIN, ad, tid);
      stage128(Bbase + (kt + 2) * 64, DIN, bd, tid);
      WAITVM(8);
    } else {
      WAITVM(0);
    }
    SBAR();
  }
  #pragma unroll
  for (int mi = 0; mi < 4; ++mi)
    #pragma unroll
    for (int ni = 0; ni < 4; ++ni)
      #pragma unroll
      for (int r = 0; r < 4; ++r) {
        long row = r0 + wm * 64 + mi * 16 + (lane >> 4) * 4 + r;
        int  col = c0 + wn * 64 + ni * 16 + (lane & 15);
        uB[(size_t)row * SDIM + col] = f2bf(acc[mi][ni][r]);
      }
}

// ================= GEMM2: 256x128, 8 waves, 3-buf + MFMA/ds_read interleave ===
// (R10 structure, unchanged)
struct Frags { short8 a[4][2]; short8 b[4][2]; };

__device__ __forceinline__ void read_frags(Frags& f, const short* la, int aoff,
                                           const short* lb, int lane, int wm, int wn) {
  int lr = lane & 15, h = lane >> 4;
  #pragma unroll
  for (int kk = 0; kk < 2; ++kk) {
    int kslot = kk * 4 + h;
    #pragma unroll
    for (int mi = 0; mi < 4; ++mi) {
      int row = aoff + wm * 64 + mi * 16 + lr;
      f.a[mi][kk] = *reinterpret_cast<const short8*>(la + row * 64 + ((kslot ^ (row & 7)) << 3));
    }
    #pragma unroll
    for (int ni = 0; ni < 4; ++ni) {
      int row = wn * 64 + ni * 16 + lr;
      f.b[ni][kk] = *reinterpret_cast<const short8*>(lb + row * 64 + ((kslot ^ (row & 7)) << 3));
    }
  }
}

__device__ __forceinline__ void mfma_frags(const Frags& f, f32x4 acc[4][4]) {
  #pragma unroll
  for (int kk = 0; kk < 2; ++kk)
    #pragma unroll
    for (int mi = 0; mi < 4; ++mi)
      #pragma unroll
      for (int ni = 0; ni < 4; ++ni)
        acc[mi][ni] = __builtin_amdgcn_mfma_f32_16x16x32_bf16(f.a[mi][kk], f.b[ni][kk], acc[mi][ni], 0, 0, 0);
}

__device__ __forceinline__ void sgb_interleave() {
  #pragma unroll
  for (int i = 0; i < 16; ++i) {
    __builtin_amdgcn_sched_group_barrier(0x008, 2, 0);   // 2 MFMA
    __builtin_amdgcn_sched_group_barrier(0x100, 1, 0);   // 1 DS read
  }
}

__device__ __forceinline__ void stageA256(const short* __restrict__ g, int ld,
                                          short* l, int tid) {
  int rsub = tid >> 3;
  int slot = (tid & 7) ^ (rsub & 7);
  #pragma unroll
  for (int i = 0; i < 4; ++i) {
    int row = i * 64 + rsub;
    GLOAD16(g + (size_t)row * ld + slot * 8, l + row * 64 + (tid & 7) * 8);
  }
}
__device__ __forceinline__ void stageB128(const short* __restrict__ g, int ld,
                                          short* l, int tid) {
  int rsub = tid >> 3;
  int slot = (tid & 7) ^ (rsub & 7);
  #pragma unroll
  for (int i = 0; i < 2; ++i) {
    int row = i * 64 + rsub;
    GLOAD16(g + (size_t)row * ld + slot * 8, l + row * 64 + (tid & 7) * 8);
  }
}
__device__ __forceinline__ void stageX320(const short* __restrict__ g,
                                          short* l, int tid) {
  int rsub = tid >> 3;
  int slot = (tid & 7) ^ (rsub & 7);
  #pragma unroll
  for (int i = 0; i < 5; ++i) {
    int row = i * 64 + rsub;
    GLOAD16(g + (size_t)row * DIN + slot * 8, l + row * 64 + (tid & 7) * 8);
  }
}

__global__ __launch_bounds__(512, 2) void k_gemm_out(const short* __restrict__ hs,
                                                     const short* __restrict__ Xp,
                                                     const short* __restrict__ Ct,
                                                     const short* __restrict__ Mt,
                                                     float* __restrict__ out) {
  __shared__ __attribute__((aligned(16))) short lds[81920];
  short* const P0  = lds;
  short* const P1  = lds + 24576;
  short* const P2  = lds + 49152;
  short* const Xs0 = lds;
  short* const Xs1 = lds + 20480;
  short* const PM0 = lds + 57344;
  short* const PM1 = lds + 65536;
  short* const PM2 = lds + 73728;
  int tid = threadIdx.x, lane = tid & 63, w = tid >> 6;
  int wm = w >> 1, wn = w & 1;                  // 4M x 2N waves, 64x64 each
  int bid = blockIdx.x;
  int sw  = (bid & 7) * 32 + (bid >> 3);        // XCD-bijective over 256
  long r0 = (long)(sw & 63) * 256;
  int  c0 = (sw >> 6) * 128;
  int  b  = (int)(r0 >> 11);
  const short* hsA = hs + (size_t)r0 * SDIM;
  const short* CtB = Ct + (size_t)c0 * SDIM;
  const short* Xa  = Xp + (size_t)(r0 + 16 * (b + 1) - 16) * DIN;
  const short* MtB = Mt + (size_t)c0 * DIN;

  const f32x4 z4 = {0.f, 0.f, 0.f, 0.f};
  f32x4 acc[4][4];
  #pragma unroll
  for (int mi = 0; mi < 4; ++mi)
    #pragma unroll
    for (int ni = 0; ni < 4; ++ni) acc[mi][ni] = z4;

  Frags fr[2];

  // ---- prologue: stage tiles 0,1,2; read frags(0) ----
  stageA256(hsA,        SDIM, P0, tid);  stageB128(CtB,        SDIM, P0 + 16384, tid);
  stageA256(hsA + 64,   SDIM, P1, tid);  stageB128(CtB + 64,   SDIM, P1 + 16384, tid);
  stageA256(hsA + 128,  SDIM, P2, tid);  stageB128(CtB + 128,  SDIM, P2 + 16384, tid);
  WAITVM(6);                 // tiles 0,1 landed; tile 2 in flight
  SBAR();
  read_frags(fr[0], P0, 0, P0 + 16384, lane, wm, wn);

  // ---- phase 1: hs @ Ct^T, 16 steps ----
  #pragma unroll
  for (int s = 0; s < 16; ++s) {
    __builtin_amdgcn_s_setprio(1);
    mfma_frags(fr[s & 1], acc);
    if (s < 15) {
      const short* nb = ((s + 1) % 3 == 0) ? P0 : ((s + 1) % 3 == 1) ? P1 : P2;
      read_frags(fr[(s + 1) & 1], nb, 0, nb + 16384, lane, wm, wn);
    } else {
      read_frags(fr[0], Xs0, 16, PM0, lane, wm, wn);   // phase-2 g=0 frags
    }
    sgb_interleave();
    __builtin_amdgcn_s_setprio(0);
    LGKM0();
    SBAR();
    if (s <= 12) {
      short* sp = (s % 3 == 0) ? P0 : (s % 3 == 1) ? P1 : P2;
      stageA256(hsA + (s + 3) * 64, SDIM, sp, tid);
      stageB128(CtB + (s + 3) * 64, SDIM, sp + 16384, tid);
      WAITVM(6);               // drains tile s+2; tile s+3 in flight
    } else if (s == 13) {
      stageB128(MtB, DIN, PM0, tid);
      stageB128(MtB + (size_t)DOUT * DIN, DIN, PM1, tid);
      WAITVM(4);               // drains tile 15; M0,M1 in flight
    } else if (s == 14) {
      stageB128(MtB + (size_t)2 * DOUT * DIN, DIN, PM2, tid);
      stageX320(Xa, Xs0, tid);
      WAITVM(0);               // phase boundary: drain M0..M2 + X0
    }                           // s == 15: no stage, nothing outstanding
    SBAR();
  }

  // ---- phase 2: AR conv, 8 slices x 10 taps ----
  for (int k0 = 0; k0 < 8; ++k0) {
    int kc = k0 * 64;
    const short* xs = (k0 & 1) ? Xs1 : Xs0;
    short*       xn = (k0 & 1) ? Xs0 : Xs1;
    const short* q0 = (k0 % 3 == 0) ? PM0 : (k0 % 3 == 1) ? PM1 : PM2;
    const short* q1 = (k0 % 3 == 0) ? PM1 : (k0 % 3 == 1) ? PM2 : PM0;
    const short* q2 = (k0 % 3 == 0) ? PM2 : (k0 % 3 == 1) ? PM0 : PM1;
    #pragma unroll
    for (int j = 0; j < KX; ++j) {
      __builtin_amdgcn_s_setprio(1);
      mfma_frags(fr[j & 1], acc);
      bool do_read = (j < 9) || (k0 < 7);
      if (j < 9) {
        const short* mn = ((j + 1) % 3 == 0) ? q0 : ((j + 1) % 3 == 1) ? q1 : q2;
        read_frags(fr[(j + 1) & 1], xs, 15 - j, mn, lane, wm, wn);
      } else if (k0 < 7) {
        read_frags(fr[0], xn, 16, q1, lane, wm, wn);   // next slice tap 0
      }
      if (do_read) sgb_interleave();
      __builtin_amdgcn_s_setprio(0);
      LGKM0();
      SBAR();
      // stage M(j+3)
      if (j + 3 <= 9) {
        short* mw = (j % 3 == 0) ? (short*)q0 : (j % 3 == 1) ? (short*)q1 : (short*)q2;
        stageB128(MtB + (size_t)(j + 3) * DOUT * DIN + kc, DIN, mw, tid);
      } else if (k0 < 7) {
        short* mw = (j % 3 == 0) ? (short*)q0 : (j % 3 == 1) ? (short*)q1 : (short*)q2;
        stageB128(MtB + (size_t)(j - 7) * DOUT * DIN + kc + 64, DIN, mw, tid);
      }
      if (j == 1 && k0 < 7) stageX320(Xa + kc + 64, xn, tid);
      if (j == 1 || j == 2) {
        if (k0 < 7) { WAITVM(7); } else { WAITVM(2); }
      } else if (j >= 7) {
        if (k0 == 7) { WAITVM(0); } else { WAITVM(2); }
      } else {
        WAITVM(2);
      }
      SBAR();
    }
  }

  #pragma unroll
  for (int mi = 0; mi < 4; ++mi)
    #pragma unroll
    for (int ni = 0; ni < 4; ++ni)
      #pragma unroll
      for (int r = 0; r < 4; ++r) {
        long row = r0 + wm * 64 + mi * 16 + (lane >> 4) * 4 + r;
        int  col = c0 + wn * 64 + ni * 16 + (lane & 15);
        out[(size_t)row * DOUT + col] = acc[mi][ni][r];
      }
}

// ================= launch =================
extern "C" void kernel_launch(void* const* d_in, const int* in_sizes, int n_in,
                              void* d_out, int out_size, void* d_ws, size_t ws_size,
                              hipStream_t stream) {
  (void)in_sizes; (void)n_in; (void)out_size; (void)ws_size;
  const float* x  = (const float*)d_in[0];
  const float* h0 = (const float*)d_in[1];
  const float* A  = (const float*)d_in[2];
  const float* B  = (const float*)d_in[3];
  const float* C  = (const float*)d_in[4];
  const float* M  = (const float*)d_in[5];
  float* out = (float*)d_out;
  char* ws = (char*)d_ws;

  short* Xp  = (short*)(ws + OFF_XP);
  short* uB  = (short*)(ws + OFF_UB);
  short* hsb = (short*)(ws + OFF_HS);
  short* Bt  = (short*)(ws + OFF_BT);
  short* Ct  = (short*)(ws + OFF_CT);
  short* Mt  = (short*)(ws + OFF_MT);
  // scan scratch inside d_out (fully overwritten by k_gemm_out afterwards)
  float* E   = out;                    // B_SZ*NC*SDIM f32 = 1 MiB
  float* Sb  = out + B_SZ * NC * SDIM; // 1 MiB

  k_conv_x<<<2048, 256, 0, stream>>>(x, Xp);
  k_transpose_bf16<<<dim3(SDIM / 32, DIN / 32), 256, 0, stream>>>(B, Bt, DIN, SDIM);
  k_transpose_bf16<<<dim3(DOUT / 32, SDIM / 32), 256, 0, stream>>>(C, Ct, SDIM, DOUT);
  k_prep_M<<<(DOUT * DIN + 255) / 256, 256, 0, stream>>>(M, Mt);

  k_gemm_uB<<<dim3(RTOT / 128, SDIM / 128), 256, 0, stream>>>(Xp, Bt, uB);

  // merged cooperative scan (E -> Sb -> hs), one launch
  {
    void* args[] = { (void*)&uB, (void*)&A, (void*)&h0,
                     (void*)&E, (void*)&Sb, (void*)&hsb };
    hipLaunchCooperativeKernel(reinterpret_cast<void*>(k_scan_all),
                               dim3(256), dim3(256), args, 0, stream);
  }

  k_gemm_out<<<256, 512, 0, stream>>>(hsb, Xp, Ct, Mt, out);
}

// Round 12
// 151.755 us; speedup vs baseline: 1.4140x; 1.4140x over previous
//
#include <hip/hip_runtime.h>

#define B_SZ   8
#define SEQ    2048
#define PSEQ   (SEQ+16)     // 16 zero pad rows before each batch
#define SDIM   1024
#define DIN    512
#define DOUT   512
#define KX     10
#define RTOT   (B_SZ*SEQ)   // 16384
#define LC     64
#define NC     (SEQ/LC)     // 32

typedef __attribute__((ext_vector_type(8))) short short8;
typedef __attribute__((ext_vector_type(4))) float f32x4;
typedef __attribute__((ext_vector_type(4))) unsigned short bfx4;

// ---- workspace layout (bytes). Xp has 64 slack rows for X-prefetch overread.
#define OFF_XP   0UL             // (B_SZ*PSEQ+64)*DIN*2 = 16,973,824
#define OFF_UB   16973824UL      // RTOT*SDIM*2 (bf16)   = 33,554,432
#define OFF_HS   50528256UL      // RTOT*SDIM*2 (bf16)   = 33,554,432
#define OFF_BT   84082688UL      // SDIM*DIN*2           = 1,048,576
#define OFF_CT   85131264UL      // DOUT*SDIM*2          = 1,048,576
#define OFF_MT   86179840UL      // KX*DOUT*DIN*2        = 5,242,880

__device__ __forceinline__ short f2bf(float f) {
  unsigned u = __builtin_bit_cast(unsigned, f);
  u += 0x7fffu + ((u >> 16) & 1u);   // RNE
  return (short)(u >> 16);
}
__device__ __forceinline__ float bf2f(unsigned short b) {
  return __builtin_bit_cast(float, (unsigned)b << 16);
}

#define GLOAD16(gp, lp) __builtin_amdgcn_global_load_lds( \
    (const __attribute__((address_space(1))) void*)(gp), \
    (__attribute__((address_space(3))) void*)(lp), 16, 0, 0)
#define WAITVM(n) asm volatile("s_waitcnt vmcnt(" #n ")" ::: "memory")
#define LGKM0()   do { asm volatile("s_waitcnt lgkmcnt(0)" ::: "memory"); \
                       __builtin_amdgcn_sched_barrier(0); } while (0)
#define SBAR() __builtin_amdgcn_s_barrier()

// ================= fused prep: conv+pad | transpose B | transpose C | prep M ==
__device__ __forceinline__ void transpose_tile(const float* __restrict__ in,
                                               short* __restrict__ out,
                                               int rows, int cols, int bxi, int byi,
                                               int tid, float (*t)[33]) {
  int bx = bxi * 32, by = byi * 32;
  int tx = tid & 31, ty = tid >> 5;
  #pragma unroll
  for (int j = 0; j < 32; j += 8)
    t[ty + j][tx] = in[(size_t)(by + ty + j) * cols + (bx + tx)];
  __syncthreads();
  #pragma unroll
  for (int j = 0; j < 32; j += 8)
    out[(size_t)(bx + ty + j) * rows + (by + tx)] = f2bf(t[tx][ty + j]);
}

__global__ void k_prep(const float* __restrict__ x,  const float* __restrict__ B,
                       const float* __restrict__ C,  const float* __restrict__ M,
                       short* __restrict__ Xp, short* __restrict__ Bt,
                       short* __restrict__ Ct, short* __restrict__ Mt) {
  __shared__ float t[32][33];
  int blk = blockIdx.x, tid = threadIdx.x;
  if (blk < 2048) {
    // conv_x f32->bf16 into padded layout + zero pad rows (grid-stride)
    const int NG = RTOT * (DIN / 8);
    const int NPAD = B_SZ * 16 * (DIN / 8);
    for (int g = blk * 256 + tid; g < NG + NPAD; g += 2048 * 256) {
      if (g < NG) {
        int r = g >> 6, c8 = g & 63;
        int b = r >> 11, tt = r & 2047;
        const float4* p = reinterpret_cast<const float4*>(x) + (size_t)g * 2;
        float4 f0 = p[0], f1 = p[1];
        short8 o;
        o[0]=f2bf(f0.x); o[1]=f2bf(f0.y); o[2]=f2bf(f0.z); o[3]=f2bf(f0.w);
        o[4]=f2bf(f1.x); o[5]=f2bf(f1.y); o[6]=f2bf(f1.z); o[7]=f2bf(f1.w);
        *reinterpret_cast<short8*>(Xp + ((size_t)(b * PSEQ + 16 + tt) * DIN + c8 * 8)) = o;
      } else {
        int idx = g - NG;
        int b = idx >> 10, rem = idx & 1023;
        int row16 = rem >> 6, c8 = rem & 63;
        const short8 z = {0,0,0,0,0,0,0,0};
        *reinterpret_cast<short8*>(Xp + ((size_t)(b * PSEQ + row16) * DIN + c8 * 8)) = z;
      }
    }
  } else if (blk < 2560) {
    int idx = blk - 2048;                 // B: [DIN x SDIM] -> Bt [SDIM][DIN]
    transpose_tile(B, Bt, DIN, SDIM, idx & 31, idx >> 5, tid, t);
  } else if (blk < 3072) {
    int idx = blk - 2560;                 // C: [SDIM x DOUT] -> Ct [DOUT][SDIM]
    transpose_tile(C, Ct, SDIM, DOUT, idx & 15, idx >> 4, tid, t);
  } else {
    int idx = (blk - 3072) * 256 + tid;   // Mt[t][o][i] = bf16(M[o][i][t])
    if (idx < DOUT * DIN) {
      int o = idx / DIN, i = idx - o * DIN;
      const float* src = M + ((size_t)o * DIN + i) * KX;
      #pragma unroll
      for (int tt = 0; tt < KX; ++tt)
        Mt[((size_t)tt * DOUT + o) * DIN + i] = f2bf(src[tt]);
    }
  }
}

// ================= chunked scan (uB is bf16) =================
__global__ void k_scan_E(const short* __restrict__ uB, const float* __restrict__ A,
                         float* __restrict__ E) {
  int blk = blockIdx.x, tid = threadIdx.x;
  int b = blk >> 5, c = blk & 31;
  int s0 = tid * 4;
  const short* base = uB + ((size_t)b * SEQ + (size_t)c * LC) * SDIM + s0;
  float a[4], h[4];
  #pragma unroll
  for (int j = 0; j < 4; ++j) { a[j] = A[s0 + j]; h[j] = 0.f; }
  for (int t = 0; t < LC; ++t) {
    bfx4 v = *reinterpret_cast<const bfx4*>(base + (size_t)t * SDIM);
    #pragma unroll
    for (int j = 0; j < 4; ++j) h[j] = fmaf(a[j], h[j], bf2f(v[j]));
  }
  float* ep = E + (size_t)blk * SDIM + s0;
  #pragma unroll
  for (int j = 0; j < 4; ++j) ep[j] = h[j];
}

// scan_h with scan_S folded in: block (b,c) derives its own boundary state
// from E[b, 0..c-1], then rescans its chunk writing hs (bf16).
__global__ void k_scan_h(const short* __restrict__ uB, const float* __restrict__ A,
                         const float* __restrict__ h0, const float* __restrict__ E,
                         short* __restrict__ hs) {
  int blk = blockIdx.x, tid = threadIdx.x;
  int b = blk >> 5, c = blk & 31;
  int s0 = tid * 4;
  float a[4], h[4], ap[4];
  #pragma unroll
  for (int j = 0; j < 4; ++j) {
    a[j] = A[s0 + j];
    float p = a[j];
    #pragma unroll
    for (int q = 0; q < 6; ++q) p *= p;   // a^64
    ap[j] = p;
    h[j] = h0[s0 + j];
  }
  // boundary recurrence: fold E[b, 0..c-1]
  const float* Eb = E + (size_t)b * NC * SDIM + s0;
  for (int c2 = 0; c2 < c; ++c2) {
    float4 ev = *reinterpret_cast<const float4*>(Eb + (size_t)c2 * SDIM);
    h[0] = fmaf(ap[0], h[0], ev.x);
    h[1] = fmaf(ap[1], h[1], ev.y);
    h[2] = fmaf(ap[2], h[2], ev.z);
    h[3] = fmaf(ap[3], h[3], ev.w);
  }
  // seeded rescan
  const short* base = uB + ((size_t)b * SEQ + (size_t)c * LC) * SDIM + s0;
  short* hbase = hs + ((size_t)b * SEQ + (size_t)c * LC) * SDIM + s0;
  for (int t = 0; t < LC; ++t) {
    bfx4 v = *reinterpret_cast<const bfx4*>(base + (size_t)t * SDIM);
    bfx4 o;
    #pragma unroll
    for (int j = 0; j < 4; ++j) {
      h[j] = fmaf(a[j], h[j], bf2f(v[j]));
      o[j] = (unsigned short)f2bf(h[j]);
    }
    *reinterpret_cast<bfx4*>(hbase + (size_t)t * SDIM) = o;
  }
}

// ================= GEMM1: 128x128, 4 waves, dbuf + counted vmcnt (proven) ====
__device__ __forceinline__ void stage128(const short* __restrict__ g, int ld,
                                         short* l, int tid) {
  int rsub = tid >> 3;
  int slot = (tid & 7) ^ (rsub & 7);
  #pragma unroll
  for (int i = 0; i < 4; ++i) {
    int row = i * 32 + rsub;
    GLOAD16(g + (size_t)row * ld + slot * 8, l + row * 64 + (tid & 7) * 8);
  }
}

__device__ __forceinline__ void mfma_tile(const short* lA, int aoff, const short* lB,
                                          int lane, int wm, int wn, f32x4 acc[4][4]) {
  int lr = lane & 15;
  int h  = lane >> 4;
  #pragma unroll
  for (int kk = 0; kk < 2; ++kk) {
    int kslot = kk * 4 + h;
    short8 af[4], bfr[4];
    #pragma unroll
    for (int mi = 0; mi < 4; ++mi) {
      int row = aoff + wm * 64 + mi * 16 + lr;
      af[mi] = *reinterpret_cast<const short8*>(lA + row * 64 + ((kslot ^ (row & 7)) << 3));
    }
    #pragma unroll
    for (int ni = 0; ni < 4; ++ni) {
      int row = wn * 64 + ni * 16 + lr;
      bfr[ni] = *reinterpret_cast<const short8*>(lB + row * 64 + ((kslot ^ (row & 7)) << 3));
    }
    __builtin_amdgcn_s_setprio(1);
    #pragma unroll
    for (int mi = 0; mi < 4; ++mi)
      #pragma unroll
      for (int ni = 0; ni < 4; ++ni)
        acc[mi][ni] = __builtin_amdgcn_mfma_f32_16x16x32_bf16(af[mi], bfr[ni], acc[mi][ni], 0, 0, 0);
    __builtin_amdgcn_s_setprio(0);
  }
}

__global__ __launch_bounds__(256) void k_gemm_uB(const short* __restrict__ Xp,
                                                 const short* __restrict__ Bt,
                                                 short* __restrict__ uB) {
  __shared__ __attribute__((aligned(16))) short lds[32768];
  short* A0 = lds;         short* B0 = lds + 8192;
  short* A1 = lds + 16384; short* B1 = lds + 24576;
  int tid = threadIdx.x, lane = tid & 63, w = tid >> 6, wm = w >> 1, wn = w & 1;
  long r0 = (long)blockIdx.x * 128;
  int  c0 = blockIdx.y * 128;
  int  b  = (int)(r0 >> 11);
  const short* Abase = Xp + (size_t)(r0 + 16 * (b + 1)) * DIN;
  const short* Bbase = Bt + (size_t)c0 * DIN;
  const f32x4 z4 = {0.f, 0.f, 0.f, 0.f};
  f32x4 acc[4][4];
  #pragma unroll
  for (int mi = 0; mi < 4; ++mi)
    #pragma unroll
    for (int ni = 0; ni < 4; ++ni) acc[mi][ni] = z4;

  stage128(Abase, DIN, A0, tid);      stage128(Bbase, DIN, B0, tid);
  stage128(Abase + 64, DIN, A1, tid); stage128(Bbase + 64, DIN, B1, tid);
  WAITVM(8);
  SBAR();
  for (int kt = 0; kt < 8; ++kt) {
    const short* a  = (kt & 1) ? A1 : A0;
    const short* bb = (kt & 1) ? B1 : B0;
    mfma_tile(a, 0, bb, lane, wm, wn, acc);
    SBAR();
    if (kt + 2 < 8) {
      short* ad = (kt & 1) ? A1 : A0;
      short* bd = (kt & 1) ? B1 : B0;
      stage128(Abase + (kt + 2) * 64, DIN, ad, tid);
      stage128(Bbase + (kt + 2) * 64, DIN, bd, tid);
      WAITVM(8);
    } else {
      WAITVM(0);
    }
    SBAR();
  }
  #pragma unroll
  for (int mi = 0; mi < 4; ++mi)
    #pragma unroll
    for (int ni = 0; ni < 4; ++ni)
      #pragma unroll
      for (int r = 0; r < 4; ++r) {
        long row = r0 + wm * 64 + mi * 16 + (lane >> 4) * 4 + r;
        int  col = c0 + wn * 64 + ni * 16 + (lane & 15);
        uB[(size_t)row * SDIM + col] = f2bf(acc[mi][ni][r]);
      }
}

// ================= GEMM2: 256x128, 8 waves, 3-buf + MFMA/ds_read interleave ===
// (R10 structure, proven at 88.8 us)
struct Frags { short8 a[4][2]; short8 b[4][2]; };

__device__ __forceinline__ void read_frags(Frags& f, const short* la, int aoff,
                                           const short* lb, int lane, int wm, int wn) {
  int lr = lane & 15, h = lane >> 4;
  #pragma unroll
  for (int kk = 0; kk < 2; ++kk) {
    int kslot = kk * 4 + h;
    #pragma unroll
    for (int mi = 0; mi < 4; ++mi) {
      int row = aoff + wm * 64 + mi * 16 + lr;
      f.a[mi][kk] = *reinterpret_cast<const short8*>(la + row * 64 + ((kslot ^ (row & 7)) << 3));
    }
    #pragma unroll
    for (int ni = 0; ni < 4; ++ni) {
      int row = wn * 64 + ni * 16 + lr;
      f.b[ni][kk] = *reinterpret_cast<const short8*>(lb + row * 64 + ((kslot ^ (row & 7)) << 3));
    }
  }
}

__device__ __forceinline__ void mfma_frags(const Frags& f, f32x4 acc[4][4]) {
  #pragma unroll
  for (int kk = 0; kk < 2; ++kk)
    #pragma unroll
    for (int mi = 0; mi < 4; ++mi)
      #pragma unroll
      for (int ni = 0; ni < 4; ++ni)
        acc[mi][ni] = __builtin_amdgcn_mfma_f32_16x16x32_bf16(f.a[mi][kk], f.b[ni][kk], acc[mi][ni], 0, 0, 0);
}

__device__ __forceinline__ void sgb_interleave() {
  #pragma unroll
  for (int i = 0; i < 16; ++i) {
    __builtin_amdgcn_sched_group_barrier(0x008, 2, 0);   // 2 MFMA
    __builtin_amdgcn_sched_group_barrier(0x100, 1, 0);   // 1 DS read
  }
}

__device__ __forceinline__ void stageA256(const short* __restrict__ g, int ld,
                                          short* l, int tid) {
  int rsub = tid >> 3;
  int slot = (tid & 7) ^ (rsub & 7);
  #pragma unroll
  for (int i = 0; i < 4; ++i) {
    int row = i * 64 + rsub;
    GLOAD16(g + (size_t)row * ld + slot * 8, l + row * 64 + (tid & 7) * 8);
  }
}
__device__ __forceinline__ void stageB128(const short* __restrict__ g, int ld,
                                          short* l, int tid) {
  int rsub = tid >> 3;
  int slot = (tid & 7) ^ (rsub & 7);
  #pragma unroll
  for (int i = 0; i < 2; ++i) {
    int row = i * 64 + rsub;
    GLOAD16(g + (size_t)row * ld + slot * 8, l + row * 64 + (tid & 7) * 8);
  }
}
__device__ __forceinline__ void stageX320(const short* __restrict__ g,
                                          short* l, int tid) {
  int rsub = tid >> 3;
  int slot = (tid & 7) ^ (rsub & 7);
  #pragma unroll
  for (int i = 0; i < 5; ++i) {
    int row = i * 64 + rsub;
    GLOAD16(g + (size_t)row * DIN + slot * 8, l + row * 64 + (tid & 7) * 8);
  }
}

__global__ __launch_bounds__(512, 2) void k_gemm_out(const short* __restrict__ hs,
                                                     const short* __restrict__ Xp,
                                                     const short* __restrict__ Ct,
                                                     const short* __restrict__ Mt,
                                                     float* __restrict__ out) {
  __shared__ __attribute__((aligned(16))) short lds[81920];
  short* const P0  = lds;
  short* const P1  = lds + 24576;
  short* const P2  = lds + 49152;
  short* const Xs0 = lds;
  short* const Xs1 = lds + 20480;
  short* const PM0 = lds + 57344;
  short* const PM1 = lds + 65536;
  short* const PM2 = lds + 73728;
  int tid = threadIdx.x, lane = tid & 63, w = tid >> 6;
  int wm = w >> 1, wn = w & 1;                  // 4M x 2N waves, 64x64 each
  int bid = blockIdx.x;
  int sw  = (bid & 7) * 32 + (bid >> 3);        // XCD-bijective over 256
  long r0 = (long)(sw & 63) * 256;
  int  c0 = (sw >> 6) * 128;
  int  b  = (int)(r0 >> 11);
  const short* hsA = hs + (size_t)r0 * SDIM;
  const short* CtB = Ct + (size_t)c0 * SDIM;
  const short* Xa  = Xp + (size_t)(r0 + 16 * (b + 1) - 16) * DIN;
  const short* MtB = Mt + (size_t)c0 * DIN;

  const f32x4 z4 = {0.f, 0.f, 0.f, 0.f};
  f32x4 acc[4][4];
  #pragma unroll
  for (int mi = 0; mi < 4; ++mi)
    #pragma unroll
    for (int ni = 0; ni < 4; ++ni) acc[mi][ni] = z4;

  Frags fr[2];

  // ---- prologue: stage tiles 0,1,2; read frags(0) ----
  stageA256(hsA,        SDIM, P0, tid);  stageB128(CtB,        SDIM, P0 + 16384, tid);
  stageA256(hsA + 64,   SDIM, P1, tid);  stageB128(CtB + 64,   SDIM, P1 + 16384, tid);
  stageA256(hsA + 128,  SDIM, P2, tid);  stageB128(CtB + 128,  SDIM, P2 + 16384, tid);
  WAITVM(6);                 // tiles 0,1 landed; tile 2 in flight
  SBAR();
  read_frags(fr[0], P0, 0, P0 + 16384, lane, wm, wn);

  // ---- phase 1: hs @ Ct^T, 16 steps ----
  #pragma unroll
  for (int s = 0; s < 16; ++s) {
    __builtin_amdgcn_s_setprio(1);
    mfma_frags(fr[s & 1], acc);
    if (s < 15) {
      const short* nb = ((s + 1) % 3 == 0) ? P0 : ((s + 1) % 3 == 1) ? P1 : P2;
      read_frags(fr[(s + 1) & 1], nb, 0, nb + 16384, lane, wm, wn);
    } else {
      read_frags(fr[0], Xs0, 16, PM0, lane, wm, wn);   // phase-2 g=0 frags
    }
    sgb_interleave();
    __builtin_amdgcn_s_setprio(0);
    LGKM0();
    SBAR();
    if (s <= 12) {
      short* sp = (s % 3 == 0) ? P0 : (s % 3 == 1) ? P1 : P2;
      stageA256(hsA + (s + 3) * 64, SDIM, sp, tid);
      stageB128(CtB + (s + 3) * 64, SDIM, sp + 16384, tid);
      WAITVM(6);               // drains tile s+2; tile s+3 in flight
    } else if (s == 13) {
      stageB128(MtB, DIN, PM0, tid);
      stageB128(MtB + (size_t)DOUT * DIN, DIN, PM1, tid);
      WAITVM(4);               // drains tile 15; M0,M1 in flight
    } else if (s == 14) {
      stageB128(MtB + (size_t)2 * DOUT * DIN, DIN, PM2, tid);
      stageX320(Xa, Xs0, tid);
      WAITVM(0);               // phase boundary: drain M0..M2 + X0
    }                           // s == 15: no stage, nothing outstanding
    SBAR();
  }

  // ---- phase 2: AR conv, 8 slices x 10 taps ----
  for (int k0 = 0; k0 < 8; ++k0) {
    int kc = k0 * 64;
    const short* xs = (k0 & 1) ? Xs1 : Xs0;
    short*       xn = (k0 & 1) ? Xs0 : Xs1;
    const short* q0 = (k0 % 3 == 0) ? PM0 : (k0 % 3 == 1) ? PM1 : PM2;
    const short* q1 = (k0 % 3 == 0) ? PM1 : (k0 % 3 == 1) ? PM2 : PM0;
    const short* q2 = (k0 % 3 == 0) ? PM2 : (k0 % 3 == 1) ? PM0 : PM1;
    #pragma unroll
    for (int j = 0; j < KX; ++j) {
      __builtin_amdgcn_s_setprio(1);
      mfma_frags(fr[j & 1], acc);
      bool do_read = (j < 9) || (k0 < 7);
      if (j < 9) {
        const short* mn = ((j + 1) % 3 == 0) ? q0 : ((j + 1) % 3 == 1) ? q1 : q2;
        read_frags(fr[(j + 1) & 1], xs, 15 - j, mn, lane, wm, wn);
      } else if (k0 < 7) {
        read_frags(fr[0], xn, 16, q1, lane, wm, wn);   // next slice tap 0
      }
      if (do_read) sgb_interleave();
      __builtin_amdgcn_s_setprio(0);
      LGKM0();
      SBAR();
      // stage M(j+3)
      if (j + 3 <= 9) {
        short* mw = (j % 3 == 0) ? (short*)q0 : (j % 3 == 1) ? (short*)q1 : (short*)q2;
        stageB128(MtB + (size_t)(j + 3) * DOUT * DIN + kc, DIN, mw, tid);
      } else if (k0 < 7) {
        short* mw = (j % 3 == 0) ? (short*)q0 : (j % 3 == 1) ? (short*)q1 : (short*)q2;
        stageB128(MtB + (size_t)(j - 7) * DOUT * DIN + kc + 64, DIN, mw, tid);
      }
      if (j == 1 && k0 < 7) stageX320(Xa + kc + 64, xn, tid);
      if (j == 1 || j == 2) {
        if (k0 < 7) { WAITVM(7); } else { WAITVM(2); }
      } else if (j >= 7) {
        if (k0 == 7) { WAITVM(0); } else { WAITVM(2); }
      } else {
        WAITVM(2);
      }
      SBAR();
    }
  }

  #pragma unroll
  for (int mi = 0; mi < 4; ++mi)
    #pragma unroll
    for (int ni = 0; ni < 4; ++ni)
      #pragma unroll
      for (int r = 0; r < 4; ++r) {
        long row = r0 + wm * 64 + mi * 16 + (lane >> 4) * 4 + r;
        int  col = c0 + wn * 64 + ni * 16 + (lane & 15);
        out[(size_t)row * DOUT + col] = acc[mi][ni][r];
      }
}

// ================= launch =================
extern "C" void kernel_launch(void* const* d_in, const int* in_sizes, int n_in,
                              void* d_out, int out_size, void* d_ws, size_t ws_size,
                              hipStream_t stream) {
  (void)in_sizes; (void)n_in; (void)out_size; (void)ws_size;
  const float* x  = (const float*)d_in[0];
  const float* h0 = (const float*)d_in[1];
  const float* A  = (const float*)d_in[2];
  const float* B  = (const float*)d_in[3];
  const float* C  = (const float*)d_in[4];
  const float* M  = (const float*)d_in[5];
  float* out = (float*)d_out;
  char* ws = (char*)d_ws;

  short* Xp  = (short*)(ws + OFF_XP);
  short* uB  = (short*)(ws + OFF_UB);
  short* hsb = (short*)(ws + OFF_HS);
  short* Bt  = (short*)(ws + OFF_BT);
  short* Ct  = (short*)(ws + OFF_CT);
  short* Mt  = (short*)(ws + OFF_MT);
  // scan scratch inside d_out (fully overwritten by k_gemm_out afterwards)
  float* E   = out;                    // B_SZ*NC*SDIM f32 = 1 MiB

  k_prep<<<4096, 256, 0, stream>>>(x, B, C, M, Xp, Bt, Ct, Mt);
  k_gemm_uB<<<dim3(RTOT / 128, SDIM / 128), 256, 0, stream>>>(Xp, Bt, uB);
  k_scan_E<<<B_SZ * NC, 256, 0, stream>>>(uB, A, E);
  k_scan_h<<<B_SZ * NC, 256, 0, stream>>>(uB, A, h0, E, hsb);
  k_gemm_out<<<256, 512, 0, stream>>>(hsb, Xp, Ct, Mt, out);
}

// Round 13
// 147.004 us; speedup vs baseline: 1.4597x; 1.0323x over previous
//
#include <hip/hip_runtime.h>

#define B_SZ   8
#define SEQ    2048
#define PSEQ   (SEQ+16)     // 16 zero pad rows before each batch
#define SDIM   1024
#define DIN    512
#define DOUT   512
#define KX     10
#define RTOT   (B_SZ*SEQ)   // 16384
#define LC     64
#define NC     (SEQ/LC)     // 32

typedef __attribute__((ext_vector_type(8))) short short8;
typedef __attribute__((ext_vector_type(4))) float f32x4;
typedef __attribute__((ext_vector_type(4))) unsigned short bfx4;

// ---- workspace layout (bytes). Xp has 64 slack rows for X-prefetch overread.
#define OFF_XP   0UL             // (B_SZ*PSEQ+64)*DIN*2 = 16,973,824
#define OFF_UB   16973824UL      // RTOT*SDIM*2 (bf16)   = 33,554,432
#define OFF_HS   50528256UL      // RTOT*SDIM*2 (bf16)   = 33,554,432
#define OFF_BT   84082688UL      // SDIM*DIN*2           = 1,048,576
#define OFF_CT   85131264UL      // DOUT*SDIM*2          = 1,048,576
#define OFF_MT   86179840UL      // KX*DOUT*DIN*2        = 5,242,880

__device__ __forceinline__ short f2bf(float f) {
  unsigned u = __builtin_bit_cast(unsigned, f);
  u += 0x7fffu + ((u >> 16) & 1u);   // RNE
  return (short)(u >> 16);
}
__device__ __forceinline__ float bf2f(unsigned short b) {
  return __builtin_bit_cast(float, (unsigned)b << 16);
}

#define GLOAD16(gp, lp) __builtin_amdgcn_global_load_lds( \
    (const __attribute__((address_space(1))) void*)(gp), \
    (__attribute__((address_space(3))) void*)(lp), 16, 0, 0)
#define WAITVM(n) asm volatile("s_waitcnt vmcnt(" #n ")" ::: "memory")
#define LGKM0()   do { asm volatile("s_waitcnt lgkmcnt(0)" ::: "memory"); \
                       __builtin_amdgcn_sched_barrier(0); } while (0)
#define SBAR() __builtin_amdgcn_s_barrier()

// ================= prep1: conv+pad x | transpose B =================
__global__ void k_prep1(const float* __restrict__ x, const float* __restrict__ B,
                        short* __restrict__ Xp, short* __restrict__ Bt) {
  __shared__ float t[32][33];
  int blk = blockIdx.x, tid = threadIdx.x;
  if (blk < 2048) {
    const int NG = RTOT * (DIN / 8);
    const int NPAD = B_SZ * 16 * (DIN / 8);
    for (int g = blk * 256 + tid; g < NG + NPAD; g += 2048 * 256) {
      if (g < NG) {
        int r = g >> 6, c8 = g & 63;
        int b = r >> 11, tt = r & 2047;
        const float4* p = reinterpret_cast<const float4*>(x) + (size_t)g * 2;
        float4 f0 = p[0], f1 = p[1];
        short8 o;
        o[0]=f2bf(f0.x); o[1]=f2bf(f0.y); o[2]=f2bf(f0.z); o[3]=f2bf(f0.w);
        o[4]=f2bf(f1.x); o[5]=f2bf(f1.y); o[6]=f2bf(f1.z); o[7]=f2bf(f1.w);
        *reinterpret_cast<short8*>(Xp + ((size_t)(b * PSEQ + 16 + tt) * DIN + c8 * 8)) = o;
      } else {
        int idx = g - NG;
        int b = idx >> 10, rem = idx & 1023;
        int row16 = rem >> 6, c8 = rem & 63;
        const short8 z = {0,0,0,0,0,0,0,0};
        *reinterpret_cast<short8*>(Xp + ((size_t)(b * PSEQ + row16) * DIN + c8 * 8)) = z;
      }
    }
  } else {
    int idx = blk - 2048;                 // B: [DIN x SDIM] -> Bt [SDIM][DIN]
    int bx = (idx & 31) * 32, by = (idx >> 5) * 32;
    int tx = tid & 31, ty = tid >> 5;
    #pragma unroll
    for (int j = 0; j < 32; j += 8)
      t[ty + j][tx] = B[(size_t)(by + ty + j) * SDIM + (bx + tx)];
    __syncthreads();
    #pragma unroll
    for (int j = 0; j < 32; j += 8)
      Bt[(size_t)(bx + ty + j) * DIN + (by + tx)] = f2bf(t[tx][ty + j]);
  }
}

// ================= scan_h (+S folded) | transpose C | prep M =================
__global__ void k_scan_h(const short* __restrict__ uB, const float* __restrict__ A,
                         const float* __restrict__ h0, const float* __restrict__ E,
                         short* __restrict__ hs,
                         const float* __restrict__ C, const float* __restrict__ M,
                         short* __restrict__ Ct, short* __restrict__ Mt) {
  __shared__ float t[32][33];
  int blk = blockIdx.x, tid = threadIdx.x;
  if (blk < 256) {
    int b = blk >> 5, c = blk & 31;
    int s0 = tid * 4;
    float a[4], h[4], ap[4];
    #pragma unroll
    for (int j = 0; j < 4; ++j) {
      a[j] = A[s0 + j];
      float p = a[j];
      #pragma unroll
      for (int q = 0; q < 6; ++q) p *= p;   // a^64
      ap[j] = p;
      h[j] = h0[s0 + j];
    }
    const float* Eb = E + (size_t)b * NC * SDIM + s0;
    for (int c2 = 0; c2 < c; ++c2) {
      float4 ev = *reinterpret_cast<const float4*>(Eb + (size_t)c2 * SDIM);
      h[0] = fmaf(ap[0], h[0], ev.x);
      h[1] = fmaf(ap[1], h[1], ev.y);
      h[2] = fmaf(ap[2], h[2], ev.z);
      h[3] = fmaf(ap[3], h[3], ev.w);
    }
    const short* base = uB + ((size_t)b * SEQ + (size_t)c * LC) * SDIM + s0;
    short* hbase = hs + ((size_t)b * SEQ + (size_t)c * LC) * SDIM + s0;
    for (int tt = 0; tt < LC; ++tt) {
      bfx4 v = *reinterpret_cast<const bfx4*>(base + (size_t)tt * SDIM);
      bfx4 o;
      #pragma unroll
      for (int j = 0; j < 4; ++j) {
        h[j] = fmaf(a[j], h[j], bf2f(v[j]));
        o[j] = (unsigned short)f2bf(h[j]);
      }
      *reinterpret_cast<bfx4*>(hbase + (size_t)tt * SDIM) = o;
    }
  } else if (blk < 768) {
    int idx = blk - 256;                  // C: [SDIM x DOUT] -> Ct [DOUT][SDIM]
    int bx = (idx & 15) * 32, by = (idx >> 4) * 32;
    int tx = tid & 31, ty = tid >> 5;
    #pragma unroll
    for (int j = 0; j < 32; j += 8)
      t[ty + j][tx] = C[(size_t)(by + ty + j) * DOUT + (bx + tx)];
    __syncthreads();
    #pragma unroll
    for (int j = 0; j < 32; j += 8)
      Ct[(size_t)(bx + ty + j) * SDIM + (by + tx)] = f2bf(t[tx][ty + j]);
  } else {
    int idx = (blk - 768) * 256 + tid;    // Mt[t][o][i] = bf16(M[o][i][t])
    if (idx < DOUT * DIN) {
      int o = idx / DIN, i = idx - o * DIN;
      const float* src = M + ((size_t)o * DIN + i) * KX;
      #pragma unroll
      for (int tt = 0; tt < KX; ++tt)
        Mt[((size_t)tt * DOUT + o) * DIN + i] = f2bf(src[tt]);
    }
  }
}

// ================= GEMM1: 128x128, 4 waves, dbuf + counted vmcnt =============
// Epilogue additionally computes E[b,chunk,s] (zero-state 64-row scan) from the
// f32 accumulators: wm selects the chunk; w(t)=a^(63-t) factorizes over (mi,h,r).
__device__ __forceinline__ void stage128(const short* __restrict__ g, int ld,
                                         short* l, int tid) {
  int rsub = tid >> 3;
  int slot = (tid & 7) ^ (rsub & 7);
  #pragma unroll
  for (int i = 0; i < 4; ++i) {
    int row = i * 32 + rsub;
    GLOAD16(g + (size_t)row * ld + slot * 8, l + row * 64 + (tid & 7) * 8);
  }
}

__device__ __forceinline__ void mfma_tile(const short* lA, int aoff, const short* lB,
                                          int lane, int wm, int wn, f32x4 acc[4][4]) {
  int lr = lane & 15;
  int h  = lane >> 4;
  #pragma unroll
  for (int kk = 0; kk < 2; ++kk) {
    int kslot = kk * 4 + h;
    short8 af[4], bfr[4];
    #pragma unroll
    for (int mi = 0; mi < 4; ++mi) {
      int row = aoff + wm * 64 + mi * 16 + lr;
      af[mi] = *reinterpret_cast<const short8*>(lA + row * 64 + ((kslot ^ (row & 7)) << 3));
    }
    #pragma unroll
    for (int ni = 0; ni < 4; ++ni) {
      int row = wn * 64 + ni * 16 + lr;
      bfr[ni] = *reinterpret_cast<const short8*>(lB + row * 64 + ((kslot ^ (row & 7)) << 3));
    }
    __builtin_amdgcn_s_setprio(1);
    #pragma unroll
    for (int mi = 0; mi < 4; ++mi)
      #pragma unroll
      for (int ni = 0; ni < 4; ++ni)
        acc[mi][ni] = __builtin_amdgcn_mfma_f32_16x16x32_bf16(af[mi], bfr[ni], acc[mi][ni], 0, 0, 0);
    __builtin_amdgcn_s_setprio(0);
  }
}

__global__ __launch_bounds__(256) void k_gemm_uB(const short* __restrict__ Xp,
                                                 const short* __restrict__ Bt,
                                                 short* __restrict__ uB,
                                                 const float* __restrict__ Adecay,
                                                 float* __restrict__ E) {
  __shared__ __attribute__((aligned(16))) short lds[32768];
  short* A0 = lds;         short* B0 = lds + 8192;
  short* A1 = lds + 16384; short* B1 = lds + 24576;
  int tid = threadIdx.x, lane = tid & 63, w = tid >> 6, wm = w >> 1, wn = w & 1;
  long r0 = (long)blockIdx.x * 128;
  int  c0 = blockIdx.y * 128;
  int  b  = (int)(r0 >> 11);
  const short* Abase = Xp + (size_t)(r0 + 16 * (b + 1)) * DIN;
  const short* Bbase = Bt + (size_t)c0 * DIN;
  const f32x4 z4 = {0.f, 0.f, 0.f, 0.f};
  f32x4 acc[4][4];
  #pragma unroll
  for (int mi = 0; mi < 4; ++mi)
    #pragma unroll
    for (int ni = 0; ni < 4; ++ni) acc[mi][ni] = z4;

  stage128(Abase, DIN, A0, tid);      stage128(Bbase, DIN, B0, tid);
  stage128(Abase + 64, DIN, A1, tid); stage128(Bbase + 64, DIN, B1, tid);
  WAITVM(8);
  SBAR();
  for (int kt = 0; kt < 8; ++kt) {
    const short* a  = (kt & 1) ? A1 : A0;
    const short* bb = (kt & 1) ? B1 : B0;
    mfma_tile(a, 0, bb, lane, wm, wn, acc);
    SBAR();
    if (kt + 2 < 8) {
      short* ad = (kt & 1) ? A1 : A0;
      short* bd = (kt & 1) ? B1 : B0;
      stage128(Abase + (kt + 2) * 64, DIN, ad, tid);
      stage128(Bbase + (kt + 2) * 64, DIN, bd, tid);
      WAITVM(8);
    } else {
      WAITVM(0);
    }
    SBAR();
  }
  int h = lane >> 4;
  // uB write
  #pragma unroll
  for (int mi = 0; mi < 4; ++mi)
    #pragma unroll
    for (int ni = 0; ni < 4; ++ni)
      #pragma unroll
      for (int r = 0; r < 4; ++r) {
        long row = r0 + wm * 64 + mi * 16 + h * 4 + r;
        int  col = c0 + wn * 64 + ni * 16 + (lane & 15);
        uB[(size_t)row * SDIM + col] = f2bf(acc[mi][ni][r]);
      }
  // E epilogue: chunk = r0/64 + wm; E[b][c][col] = sum_t a^(63-t) u_t
  int cch = (int)((r0 >> 6) & 31) + wm;
  #pragma unroll
  for (int ni = 0; ni < 4; ++ni) {
    int col = c0 + wn * 64 + ni * 16 + (lane & 15);
    float a  = Adecay[col];
    float a2 = a * a, a3 = a2 * a;
    float A4 = a2 * a2;
    float A16 = A4 * A4; A16 = A16 * A16;
    float P16_2 = A16 * A16, P16_3 = P16_2 * A16;
    float Q4 = (h == 3) ? 1.f : (h == 2) ? A4 : (h == 1) ? A4 * A4 : A4 * A4 * A4;
    float cm0 = fmaf(acc[0][ni][0], a3, fmaf(acc[0][ni][1], a2, fmaf(acc[0][ni][2], a, acc[0][ni][3])));
    float cm1 = fmaf(acc[1][ni][0], a3, fmaf(acc[1][ni][1], a2, fmaf(acc[1][ni][2], a, acc[1][ni][3])));
    float cm2 = fmaf(acc[2][ni][0], a3, fmaf(acc[2][ni][1], a2, fmaf(acc[2][ni][2], a, acc[2][ni][3])));
    float cm3 = fmaf(acc[3][ni][0], a3, fmaf(acc[3][ni][1], a2, fmaf(acc[3][ni][2], a, acc[3][ni][3])));
    float L = fmaf(cm0, P16_3, fmaf(cm1, P16_2, fmaf(cm2, A16, cm3)));
    L *= Q4;
    L += __shfl_xor(L, 16);
    L += __shfl_xor(L, 32);
    if (h == 0) E[((size_t)b * NC + cch) * SDIM + col] = L;
  }
}

// ================= GEMM2: 256x128, 8 waves, 3-buf + MFMA/ds_read interleave ===
// (R10 structure, proven at 88.8 us)
struct Frags { short8 a[4][2]; short8 b[4][2]; };

__device__ __forceinline__ void read_frags(Frags& f, const short* la, int aoff,
                                           const short* lb, int lane, int wm, int wn) {
  int lr = lane & 15, h = lane >> 4;
  #pragma unroll
  for (int kk = 0; kk < 2; ++kk) {
    int kslot = kk * 4 + h;
    #pragma unroll
    for (int mi = 0; mi < 4; ++mi) {
      int row = aoff + wm * 64 + mi * 16 + lr;
      f.a[mi][kk] = *reinterpret_cast<const short8*>(la + row * 64 + ((kslot ^ (row & 7)) << 3));
    }
    #pragma unroll
    for (int ni = 0; ni < 4; ++ni) {
      int row = wn * 64 + ni * 16 + lr;
      f.b[ni][kk] = *reinterpret_cast<const short8*>(lb + row * 64 + ((kslot ^ (row & 7)) << 3));
    }
  }
}

__device__ __forceinline__ void mfma_frags(const Frags& f, f32x4 acc[4][4]) {
  #pragma unroll
  for (int kk = 0; kk < 2; ++kk)
    #pragma unroll
    for (int mi = 0; mi < 4; ++mi)
      #pragma unroll
      for (int ni = 0; ni < 4; ++ni)
        acc[mi][ni] = __builtin_amdgcn_mfma_f32_16x16x32_bf16(f.a[mi][kk], f.b[ni][kk], acc[mi][ni], 0, 0, 0);
}

__device__ __forceinline__ void sgb_interleave() {
  #pragma unroll
  for (int i = 0; i < 16; ++i) {
    __builtin_amdgcn_sched_group_barrier(0x008, 2, 0);   // 2 MFMA
    __builtin_amdgcn_sched_group_barrier(0x100, 1, 0);   // 1 DS read
  }
}

__device__ __forceinline__ void stageA256(const short* __restrict__ g, int ld,
                                          short* l, int tid) {
  int rsub = tid >> 3;
  int slot = (tid & 7) ^ (rsub & 7);
  #pragma unroll
  for (int i = 0; i < 4; ++i) {
    int row = i * 64 + rsub;
    GLOAD16(g + (size_t)row * ld + slot * 8, l + row * 64 + (tid & 7) * 8);
  }
}
__device__ __forceinline__ void stageB128(const short* __restrict__ g, int ld,
                                          short* l, int tid) {
  int rsub = tid >> 3;
  int slot = (tid & 7) ^ (rsub & 7);
  #pragma unroll
  for (int i = 0; i < 2; ++i) {
    int row = i * 64 + rsub;
    GLOAD16(g + (size_t)row * ld + slot * 8, l + row * 64 + (tid & 7) * 8);
  }
}
__device__ __forceinline__ void stageX320(const short* __restrict__ g,
                                          short* l, int tid) {
  int rsub = tid >> 3;
  int slot = (tid & 7) ^ (rsub & 7);
  #pragma unroll
  for (int i = 0; i < 5; ++i) {
    int row = i * 64 + rsub;
    GLOAD16(g + (size_t)row * DIN + slot * 8, l + row * 64 + (tid & 7) * 8);
  }
}

__global__ __launch_bounds__(512, 2) void k_gemm_out(const short* __restrict__ hs,
                                                     const short* __restrict__ Xp,
                                                     const short* __restrict__ Ct,
                                                     const short* __restrict__ Mt,
                                                     float* __restrict__ out) {
  __shared__ __attribute__((aligned(16))) short lds[81920];
  short* const P0  = lds;
  short* const P1  = lds + 24576;
  short* const P2  = lds + 49152;
  short* const Xs0 = lds;
  short* const Xs1 = lds + 20480;
  short* const PM0 = lds + 57344;
  short* const PM1 = lds + 65536;
  short* const PM2 = lds + 73728;
  int tid = threadIdx.x, lane = tid & 63, w = tid >> 6;
  int wm = w >> 1, wn = w & 1;                  // 4M x 2N waves, 64x64 each
  int bid = blockIdx.x;
  int sw  = (bid & 7) * 32 + (bid >> 3);        // XCD-bijective over 256
  long r0 = (long)(sw & 63) * 256;
  int  c0 = (sw >> 6) * 128;
  int  b  = (int)(r0 >> 11);
  const short* hsA = hs + (size_t)r0 * SDIM;
  const short* CtB = Ct + (size_t)c0 * SDIM;
  const short* Xa  = Xp + (size_t)(r0 + 16 * (b + 1) - 16) * DIN;
  const short* MtB = Mt + (size_t)c0 * DIN;

  const f32x4 z4 = {0.f, 0.f, 0.f, 0.f};
  f32x4 acc[4][4];
  #pragma unroll
  for (int mi = 0; mi < 4; ++mi)
    #pragma unroll
    for (int ni = 0; ni < 4; ++ni) acc[mi][ni] = z4;

  Frags fr[2];

  // ---- prologue: stage tiles 0,1,2; read frags(0) ----
  stageA256(hsA,        SDIM, P0, tid);  stageB128(CtB,        SDIM, P0 + 16384, tid);
  stageA256(hsA + 64,   SDIM, P1, tid);  stageB128(CtB + 64,   SDIM, P1 + 16384, tid);
  stageA256(hsA + 128,  SDIM, P2, tid);  stageB128(CtB + 128,  SDIM, P2 + 16384, tid);
  WAITVM(6);                 // tiles 0,1 landed; tile 2 in flight
  SBAR();
  read_frags(fr[0], P0, 0, P0 + 16384, lane, wm, wn);

  // ---- phase 1: hs @ Ct^T, 16 steps ----
  #pragma unroll
  for (int s = 0; s < 16; ++s) {
    __builtin_amdgcn_s_setprio(1);
    mfma_frags(fr[s & 1], acc);
    if (s < 15) {
      const short* nb = ((s + 1) % 3 == 0) ? P0 : ((s + 1) % 3 == 1) ? P1 : P2;
      read_frags(fr[(s + 1) & 1], nb, 0, nb + 16384, lane, wm, wn);
    } else {
      read_frags(fr[0], Xs0, 16, PM0, lane, wm, wn);   // phase-2 g=0 frags
    }
    sgb_interleave();
    __builtin_amdgcn_s_setprio(0);
    LGKM0();
    SBAR();
    if (s <= 12) {
      short* sp = (s % 3 == 0) ? P0 : (s % 3 == 1) ? P1 : P2;
      stageA256(hsA + (s + 3) * 64, SDIM, sp, tid);
      stageB128(CtB + (s + 3) * 64, SDIM, sp + 16384, tid);
      WAITVM(6);               // drains tile s+2; tile s+3 in flight
    } else if (s == 13) {
      stageB128(MtB, DIN, PM0, tid);
      stageB128(MtB + (size_t)DOUT * DIN, DIN, PM1, tid);
      WAITVM(4);               // drains tile 15; M0,M1 in flight
    } else if (s == 14) {
      stageB128(MtB + (size_t)2 * DOUT * DIN, DIN, PM2, tid);
      stageX320(Xa, Xs0, tid);
      WAITVM(0);               // phase boundary: drain M0..M2 + X0
    }                           // s == 15: no stage, nothing outstanding
    SBAR();
  }

  // ---- phase 2: AR conv, 8 slices x 10 taps ----
  for (int k0 = 0; k0 < 8; ++k0) {
    int kc = k0 * 64;
    const short* xs = (k0 & 1) ? Xs1 : Xs0;
    short*       xn = (k0 & 1) ? Xs0 : Xs1;
    const short* q0 = (k0 % 3 == 0) ? PM0 : (k0 % 3 == 1) ? PM1 : PM2;
    const short* q1 = (k0 % 3 == 0) ? PM1 : (k0 % 3 == 1) ? PM2 : PM0;
    const short* q2 = (k0 % 3 == 0) ? PM2 : (k0 % 3 == 1) ? PM0 : PM1;
    #pragma unroll
    for (int j = 0; j < KX; ++j) {
      __builtin_amdgcn_s_setprio(1);
      mfma_frags(fr[j & 1], acc);
      bool do_read = (j < 9) || (k0 < 7);
      if (j < 9) {
        const short* mn = ((j + 1) % 3 == 0) ? q0 : ((j + 1) % 3 == 1) ? q1 : q2;
        read_frags(fr[(j + 1) & 1], xs, 15 - j, mn, lane, wm, wn);
      } else if (k0 < 7) {
        read_frags(fr[0], xn, 16, q1, lane, wm, wn);   // next slice tap 0
      }
      if (do_read) sgb_interleave();
      __builtin_amdgcn_s_setprio(0);
      LGKM0();
      SBAR();
      // stage M(j+3)
      if (j + 3 <= 9) {
        short* mw = (j % 3 == 0) ? (short*)q0 : (j % 3 == 1) ? (short*)q1 : (short*)q2;
        stageB128(MtB + (size_t)(j + 3) * DOUT * DIN + kc, DIN, mw, tid);
      } else if (k0 < 7) {
        short* mw = (j % 3 == 0) ? (short*)q0 : (j % 3 == 1) ? (short*)q1 : (short*)q2;
        stageB128(MtB + (size_t)(j - 7) * DOUT * DIN + kc + 64, DIN, mw, tid);
      }
      if (j == 1 && k0 < 7) stageX320(Xa + kc + 64, xn, tid);
      if (j == 1 || j == 2) {
        if (k0 < 7) { WAITVM(7); } else { WAITVM(2); }
      } else if (j >= 7) {
        if (k0 == 7) { WAITVM(0); } else { WAITVM(2); }
      } else {
        WAITVM(2);
      }
      SBAR();
    }
  }

  #pragma unroll
  for (int mi = 0; mi < 4; ++mi)
    #pragma unroll
    for (int ni = 0; ni < 4; ++ni)
      #pragma unroll
      for (int r = 0; r < 4; ++r) {
        long row = r0 + wm * 64 + mi * 16 + (lane >> 4) * 4 + r;
        int  col = c0 + wn * 64 + ni * 16 + (lane & 15);
        out[(size_t)row * DOUT + col] = acc[mi][ni][r];
      }
}

// ================= launch =================
extern "C" void kernel_launch(void* const* d_in, const int* in_sizes, int n_in,
                              void* d_out, int out_size, void* d_ws, size_t ws_size,
                              hipStream_t stream) {
  (void)in_sizes; (void)n_in; (void)out_size; (void)ws_size;
  const float* x  = (const float*)d_in[0];
  const float* h0 = (const float*)d_in[1];
  const float* A  = (const float*)d_in[2];
  const float* B  = (const float*)d_in[3];
  const float* C  = (const float*)d_in[4];
  const float* M  = (const float*)d_in[5];
  float* out = (float*)d_out;
  char* ws = (char*)d_ws;

  short* Xp  = (short*)(ws + OFF_XP);
  short* uB  = (short*)(ws + OFF_UB);
  short* hsb = (short*)(ws + OFF_HS);
  short* Bt  = (short*)(ws + OFF_BT);
  short* Ct  = (short*)(ws + OFF_CT);
  short* Mt  = (short*)(ws + OFF_MT);
  // scan scratch inside d_out (fully overwritten by k_gemm_out afterwards)
  float* E   = out;                    // B_SZ*NC*SDIM f32 = 1 MiB

  k_prep1<<<2560, 256, 0, stream>>>(x, B, Xp, Bt);
  k_gemm_uB<<<dim3(RTOT / 128, SDIM / 128), 256, 0, stream>>>(Xp, Bt, uB, A, E);
  k_scan_h<<<1792, 256, 0, stream>>>(uB, A, h0, E, hsb, C, M, Ct, Mt);
  k_gemm_out<<<256, 512, 0, stream>>>(hsb, Xp, Ct, Mt, out);
}

// Round 14
// 146.520 us; speedup vs baseline: 1.4645x; 1.0033x over previous
//
#include <hip/hip_runtime.h>

#define B_SZ   8
#define SEQ    2048
#define PSEQ   (SEQ+16)     // 16 zero pad rows before each batch
#define SDIM   1024
#define DIN    512
#define DOUT   512
#define KX     10
#define RTOT   (B_SZ*SEQ)   // 16384
#define LC     64
#define NC     (SEQ/LC)     // 32

typedef __attribute__((ext_vector_type(8))) short short8;
typedef __attribute__((ext_vector_type(4))) float f32x4;
typedef __attribute__((ext_vector_type(4))) unsigned short bfx4;

// ---- workspace layout (bytes). Xp has 64 slack rows for X-prefetch overread.
#define OFF_XP   0UL             // (B_SZ*PSEQ+64)*DIN*2 = 16,973,824
#define OFF_UB   16973824UL      // RTOT*SDIM*2 (bf16)   = 33,554,432
#define OFF_HS   50528256UL      // RTOT*SDIM*2 (bf16)   = 33,554,432
#define OFF_BT   84082688UL      // SDIM*DIN*2           = 1,048,576
#define OFF_CT   85131264UL      // DOUT*SDIM*2          = 1,048,576
#define OFF_MT   86179840UL      // KX*DOUT*DIN*2        = 5,242,880

__device__ __forceinline__ short f2bf(float f) {
  unsigned u = __builtin_bit_cast(unsigned, f);
  u += 0x7fffu + ((u >> 16) & 1u);   // RNE
  return (short)(u >> 16);
}
__device__ __forceinline__ float bf2f(unsigned short b) {
  return __builtin_bit_cast(float, (unsigned)b << 16);
}

#define GLOAD16(gp, lp) __builtin_amdgcn_global_load_lds( \
    (const __attribute__((address_space(1))) void*)(gp), \
    (__attribute__((address_space(3))) void*)(lp), 16, 0, 0)
#define WAITVM(n) asm volatile("s_waitcnt vmcnt(" #n ")" ::: "memory")
#define LGKM0()   do { asm volatile("s_waitcnt lgkmcnt(0)" ::: "memory"); \
                       __builtin_amdgcn_sched_barrier(0); } while (0)
#define SBAR() __builtin_amdgcn_s_barrier()

// ================= shared GEMM pipeline building blocks =================
struct Frags { short8 a[4][2]; short8 b[4][2]; };

__device__ __forceinline__ void read_frags(Frags& f, const short* la, int aoff,
                                           const short* lb, int lane, int wm, int wn) {
  int lr = lane & 15, h = lane >> 4;
  #pragma unroll
  for (int kk = 0; kk < 2; ++kk) {
    int kslot = kk * 4 + h;
    #pragma unroll
    for (int mi = 0; mi < 4; ++mi) {
      int row = aoff + wm * 64 + mi * 16 + lr;
      f.a[mi][kk] = *reinterpret_cast<const short8*>(la + row * 64 + ((kslot ^ (row & 7)) << 3));
    }
    #pragma unroll
    for (int ni = 0; ni < 4; ++ni) {
      int row = wn * 64 + ni * 16 + lr;
      f.b[ni][kk] = *reinterpret_cast<const short8*>(lb + row * 64 + ((kslot ^ (row & 7)) << 3));
    }
  }
}

__device__ __forceinline__ void mfma_frags(const Frags& f, f32x4 acc[4][4]) {
  #pragma unroll
  for (int kk = 0; kk < 2; ++kk)
    #pragma unroll
    for (int mi = 0; mi < 4; ++mi)
      #pragma unroll
      for (int ni = 0; ni < 4; ++ni)
        acc[mi][ni] = __builtin_amdgcn_mfma_f32_16x16x32_bf16(f.a[mi][kk], f.b[ni][kk], acc[mi][ni], 0, 0, 0);
}

__device__ __forceinline__ void sgb_interleave() {
  #pragma unroll
  for (int i = 0; i < 16; ++i) {
    __builtin_amdgcn_sched_group_barrier(0x008, 2, 0);   // 2 MFMA
    __builtin_amdgcn_sched_group_barrier(0x100, 1, 0);   // 1 DS read
  }
}

__device__ __forceinline__ void stageA256(const short* __restrict__ g, int ld,
                                          short* l, int tid) {
  int rsub = tid >> 3;
  int slot = (tid & 7) ^ (rsub & 7);
  #pragma unroll
  for (int i = 0; i < 4; ++i) {
    int row = i * 64 + rsub;
    GLOAD16(g + (size_t)row * ld + slot * 8, l + row * 64 + (tid & 7) * 8);
  }
}
__device__ __forceinline__ void stageB128(const short* __restrict__ g, int ld,
                                          short* l, int tid) {
  int rsub = tid >> 3;
  int slot = (tid & 7) ^ (rsub & 7);
  #pragma unroll
  for (int i = 0; i < 2; ++i) {
    int row = i * 64 + rsub;
    GLOAD16(g + (size_t)row * ld + slot * 8, l + row * 64 + (tid & 7) * 8);
  }
}
__device__ __forceinline__ void stageX320(const short* __restrict__ g,
                                          short* l, int tid) {
  int rsub = tid >> 3;
  int slot = (tid & 7) ^ (rsub & 7);
  #pragma unroll
  for (int i = 0; i < 5; ++i) {
    int row = i * 64 + rsub;
    GLOAD16(g + (size_t)row * DIN + slot * 8, l + row * 64 + (tid & 7) * 8);
  }
}

// ================= prep1: conv+pad x | transpose B =================
__global__ void k_prep1(const float* __restrict__ x, const float* __restrict__ B,
                        short* __restrict__ Xp, short* __restrict__ Bt) {
  __shared__ float t[32][33];
  int blk = blockIdx.x, tid = threadIdx.x;
  if (blk < 2048) {
    const int NG = RTOT * (DIN / 8);
    const int NPAD = B_SZ * 16 * (DIN / 8);
    for (int g = blk * 256 + tid; g < NG + NPAD; g += 2048 * 256) {
      if (g < NG) {
        int r = g >> 6, c8 = g & 63;
        int b = r >> 11, tt = r & 2047;
        const float4* p = reinterpret_cast<const float4*>(x) + (size_t)g * 2;
        float4 f0 = p[0], f1 = p[1];
        short8 o;
        o[0]=f2bf(f0.x); o[1]=f2bf(f0.y); o[2]=f2bf(f0.z); o[3]=f2bf(f0.w);
        o[4]=f2bf(f1.x); o[5]=f2bf(f1.y); o[6]=f2bf(f1.z); o[7]=f2bf(f1.w);
        *reinterpret_cast<short8*>(Xp + ((size_t)(b * PSEQ + 16 + tt) * DIN + c8 * 8)) = o;
      } else {
        int idx = g - NG;
        int b = idx >> 10, rem = idx & 1023;
        int row16 = rem >> 6, c8 = rem & 63;
        const short8 z = {0,0,0,0,0,0,0,0};
        *reinterpret_cast<short8*>(Xp + ((size_t)(b * PSEQ + row16) * DIN + c8 * 8)) = z;
      }
    }
  } else {
    int idx = blk - 2048;                 // B: [DIN x SDIM] -> Bt [SDIM][DIN]
    int bx = (idx & 31) * 32, by = (idx >> 5) * 32;
    int tx = tid & 31, ty = tid >> 5;
    #pragma unroll
    for (int j = 0; j < 32; j += 8)
      t[ty + j][tx] = B[(size_t)(by + ty + j) * SDIM + (bx + tx)];
    __syncthreads();
    #pragma unroll
    for (int j = 0; j < 32; j += 8)
      Bt[(size_t)(bx + ty + j) * DIN + (by + tx)] = f2bf(t[tx][ty + j]);
  }
}

// ================= scan_h (+S folded) | transpose C | prep M =================
__global__ void k_scan_h(const short* __restrict__ uB, const float* __restrict__ A,
                         const float* __restrict__ h0, const float* __restrict__ E,
                         short* __restrict__ hs,
                         const float* __restrict__ C, const float* __restrict__ M,
                         short* __restrict__ Ct, short* __restrict__ Mt) {
  __shared__ float t[32][33];
  int blk = blockIdx.x, tid = threadIdx.x;
  if (blk < 256) {
    int b = blk >> 5, c = blk & 31;
    int s0 = tid * 4;
    float a[4], h[4], ap[4];
    #pragma unroll
    for (int j = 0; j < 4; ++j) {
      a[j] = A[s0 + j];
      float p = a[j];
      #pragma unroll
      for (int q = 0; q < 6; ++q) p *= p;   // a^64
      ap[j] = p;
      h[j] = h0[s0 + j];
    }
    const float* Eb = E + (size_t)b * NC * SDIM + s0;
    for (int c2 = 0; c2 < c; ++c2) {
      float4 ev = *reinterpret_cast<const float4*>(Eb + (size_t)c2 * SDIM);
      h[0] = fmaf(ap[0], h[0], ev.x);
      h[1] = fmaf(ap[1], h[1], ev.y);
      h[2] = fmaf(ap[2], h[2], ev.z);
      h[3] = fmaf(ap[3], h[3], ev.w);
    }
    const short* base = uB + ((size_t)b * SEQ + (size_t)c * LC) * SDIM + s0;
    short* hbase = hs + ((size_t)b * SEQ + (size_t)c * LC) * SDIM + s0;
    for (int tt = 0; tt < LC; ++tt) {
      bfx4 v = *reinterpret_cast<const bfx4*>(base + (size_t)tt * SDIM);
      bfx4 o;
      #pragma unroll
      for (int j = 0; j < 4; ++j) {
        h[j] = fmaf(a[j], h[j], bf2f(v[j]));
        o[j] = (unsigned short)f2bf(h[j]);
      }
      *reinterpret_cast<bfx4*>(hbase + (size_t)tt * SDIM) = o;
    }
  } else if (blk < 768) {
    int idx = blk - 256;                  // C: [SDIM x DOUT] -> Ct [DOUT][SDIM]
    int bx = (idx & 15) * 32, by = (idx >> 4) * 32;
    int tx = tid & 31, ty = tid >> 5;
    #pragma unroll
    for (int j = 0; j < 32; j += 8)
      t[ty + j][tx] = C[(size_t)(by + ty + j) * DOUT + (bx + tx)];
    __syncthreads();
    #pragma unroll
    for (int j = 0; j < 32; j += 8)
      Ct[(size_t)(bx + ty + j) * SDIM + (by + tx)] = f2bf(t[tx][ty + j]);
  } else {
    int idx = (blk - 768) * 256 + tid;    // Mt[t][o][i] = bf16(M[o][i][t])
    if (idx < DOUT * DIN) {
      int o = idx / DIN, i = idx - o * DIN;
      const float* src = M + ((size_t)o * DIN + i) * KX;
      #pragma unroll
      for (int tt = 0; tt < KX; ++tt)
        Mt[((size_t)tt * DOUT + o) * DIN + i] = f2bf(src[tt]);
    }
  }
}

// ================= GEMM1: 256x128, 8 waves, 3-buf ring (R10 template) ========
// K = 512 -> 8 steps. Grid = 64 rowblks x 8 c-panels = 512 blocks.
// Epilogue: uB (bf16) + E[b,chunk,s] from f32 acc (wave's 64 rows = one chunk).
__global__ __launch_bounds__(512, 2) void k_gemm_uB(const short* __restrict__ Xp,
                                                    const short* __restrict__ Bt,
                                                    short* __restrict__ uB,
                                                    const float* __restrict__ Adecay,
                                                    float* __restrict__ E) {
  __shared__ __attribute__((aligned(16))) short lds[73728];   // 3 x (16384A + 8192B)
  short* const P0 = lds;
  short* const P1 = lds + 24576;
  short* const P2 = lds + 49152;
  int tid = threadIdx.x, lane = tid & 63, w = tid >> 6;
  int wm = w >> 1, wn = w & 1;                 // 4M x 2N waves, 64x64 each
  int bid = blockIdx.x;
  long r0 = (long)(bid & 63) * 256;
  int  c0 = (bid >> 6) * 128;
  int  b  = (int)(r0 >> 11);
  const short* Aa = Xp + (size_t)(r0 + 16 * (b + 1)) * DIN;
  const short* Bb = Bt + (size_t)c0 * DIN;

  const f32x4 z4 = {0.f, 0.f, 0.f, 0.f};
  f32x4 acc[4][4];
  #pragma unroll
  for (int mi = 0; mi < 4; ++mi)
    #pragma unroll
    for (int ni = 0; ni < 4; ++ni) acc[mi][ni] = z4;

  Frags fr[2];

  // prologue: stage tiles 0,1,2
  stageA256(Aa,       DIN, P0, tid);  stageB128(Bb,       DIN, P0 + 16384, tid);
  stageA256(Aa + 64,  DIN, P1, tid);  stageB128(Bb + 64,  DIN, P1 + 16384, tid);
  stageA256(Aa + 128, DIN, P2, tid);  stageB128(Bb + 128, DIN, P2 + 16384, tid);
  WAITVM(6);                  // tiles 0,1 landed; tile 2 in flight
  SBAR();
  read_frags(fr[0], P0, 0, P0 + 16384, lane, wm, wn);

  #pragma unroll
  for (int s = 0; s < 8; ++s) {
    __builtin_amdgcn_s_setprio(1);
    mfma_frags(fr[s & 1], acc);
    if (s < 7) {
      const short* nb = ((s + 1) % 3 == 0) ? P0 : ((s + 1) % 3 == 1) ? P1 : P2;
      read_frags(fr[(s + 1) & 1], nb, 0, nb + 16384, lane, wm, wn);
      sgb_interleave();
    }
    __builtin_amdgcn_s_setprio(0);
    if (s < 7) {
      LGKM0();
      SBAR();
      if (s <= 4) {
        short* sp = (s % 3 == 0) ? P0 : (s % 3 == 1) ? P1 : P2;
        stageA256(Aa + (s + 3) * 64, DIN, sp, tid);
        stageB128(Bb + (s + 3) * 64, DIN, sp + 16384, tid);
        WAITVM(6);            // drains tile s+2; tile s+3 in flight
      } else {
        WAITVM(0);            // tail: tile 7 already had a full step to land
      }
      SBAR();
    }
  }

  int h = lane >> 4;
  // uB write (bf16)
  #pragma unroll
  for (int mi = 0; mi < 4; ++mi)
    #pragma unroll
    for (int ni = 0; ni < 4; ++ni)
      #pragma unroll
      for (int r = 0; r < 4; ++r) {
        long row = r0 + wm * 64 + mi * 16 + h * 4 + r;
        int  col = c0 + wn * 64 + ni * 16 + (lane & 15);
        uB[(size_t)row * SDIM + col] = f2bf(acc[mi][ni][r]);
      }
  // E epilogue: chunk = (r0>>6)&31 + wm; E[b][c][col] = sum_t a^(63-t) u_t
  int cch = (int)((r0 >> 6) & 31) + wm;
  #pragma unroll
  for (int ni = 0; ni < 4; ++ni) {
    int col = c0 + wn * 64 + ni * 16 + (lane & 15);
    float a  = Adecay[col];
    float a2 = a * a, a3 = a2 * a;
    float A4 = a2 * a2;
    float A16 = A4 * A4; A16 = A16 * A16;
    float P16_2 = A16 * A16, P16_3 = P16_2 * A16;
    float Q4 = (h == 3) ? 1.f : (h == 2) ? A4 : (h == 1) ? A4 * A4 : A4 * A4 * A4;
    float cm0 = fmaf(acc[0][ni][0], a3, fmaf(acc[0][ni][1], a2, fmaf(acc[0][ni][2], a, acc[0][ni][3])));
    float cm1 = fmaf(acc[1][ni][0], a3, fmaf(acc[1][ni][1], a2, fmaf(acc[1][ni][2], a, acc[1][ni][3])));
    float cm2 = fmaf(acc[2][ni][0], a3, fmaf(acc[2][ni][1], a2, fmaf(acc[2][ni][2], a, acc[2][ni][3])));
    float cm3 = fmaf(acc[3][ni][0], a3, fmaf(acc[3][ni][1], a2, fmaf(acc[3][ni][2], a, acc[3][ni][3])));
    float L = fmaf(cm0, P16_3, fmaf(cm1, P16_2, fmaf(cm2, A16, cm3)));
    L *= Q4;
    L += __shfl_xor(L, 16);
    L += __shfl_xor(L, 32);
    if (h == 0) E[((size_t)b * NC + cch) * SDIM + col] = L;
  }
}

// ================= GEMM2: 256x128, 8 waves, 3-buf + MFMA/ds_read interleave ===
// (R10 structure, proven at 88.8 us)
__global__ __launch_bounds__(512, 2) void k_gemm_out(const short* __restrict__ hs,
                                                     const short* __restrict__ Xp,
                                                     const short* __restrict__ Ct,
                                                     const short* __restrict__ Mt,
                                                     float* __restrict__ out) {
  __shared__ __attribute__((aligned(16))) short lds[81920];
  short* const P0  = lds;
  short* const P1  = lds + 24576;
  short* const P2  = lds + 49152;
  short* const Xs0 = lds;
  short* const Xs1 = lds + 20480;
  short* const PM0 = lds + 57344;
  short* const PM1 = lds + 65536;
  short* const PM2 = lds + 73728;
  int tid = threadIdx.x, lane = tid & 63, w = tid >> 6;
  int wm = w >> 1, wn = w & 1;                  // 4M x 2N waves, 64x64 each
  int bid = blockIdx.x;
  int sw  = (bid & 7) * 32 + (bid >> 3);        // XCD-bijective over 256
  long r0 = (long)(sw & 63) * 256;
  int  c0 = (sw >> 6) * 128;
  int  b  = (int)(r0 >> 11);
  const short* hsA = hs + (size_t)r0 * SDIM;
  const short* CtB = Ct + (size_t)c0 * SDIM;
  const short* Xa  = Xp + (size_t)(r0 + 16 * (b + 1) - 16) * DIN;
  const short* MtB = Mt + (size_t)c0 * DIN;

  const f32x4 z4 = {0.f, 0.f, 0.f, 0.f};
  f32x4 acc[4][4];
  #pragma unroll
  for (int mi = 0; mi < 4; ++mi)
    #pragma unroll
    for (int ni = 0; ni < 4; ++ni) acc[mi][ni] = z4;

  Frags fr[2];

  // ---- prologue: stage tiles 0,1,2; read frags(0) ----
  stageA256(hsA,        SDIM, P0, tid);  stageB128(CtB,        SDIM, P0 + 16384, tid);
  stageA256(hsA + 64,   SDIM, P1, tid);  stageB128(CtB + 64,   SDIM, P1 + 16384, tid);
  stageA256(hsA + 128,  SDIM, P2, tid);  stageB128(CtB + 128,  SDIM, P2 + 16384, tid);
  WAITVM(6);                 // tiles 0,1 landed; tile 2 in flight
  SBAR();
  read_frags(fr[0], P0, 0, P0 + 16384, lane, wm, wn);

  // ---- phase 1: hs @ Ct^T, 16 steps ----
  #pragma unroll
  for (int s = 0; s < 16; ++s) {
    __builtin_amdgcn_s_setprio(1);
    mfma_frags(fr[s & 1], acc);
    if (s < 15) {
      const short* nb = ((s + 1) % 3 == 0) ? P0 : ((s + 1) % 3 == 1) ? P1 : P2;
      read_frags(fr[(s + 1) & 1], nb, 0, nb + 16384, lane, wm, wn);
    } else {
      read_frags(fr[0], Xs0, 16, PM0, lane, wm, wn);   // phase-2 g=0 frags
    }
    sgb_interleave();
    __builtin_amdgcn_s_setprio(0);
    LGKM0();
    SBAR();
    if (s <= 12) {
      short* sp = (s % 3 == 0) ? P0 : (s % 3 == 1) ? P1 : P2;
      stageA256(hsA + (s + 3) * 64, SDIM, sp, tid);
      stageB128(CtB + (s + 3) * 64, SDIM, sp + 16384, tid);
      WAITVM(6);               // drains tile s+2; tile s+3 in flight
    } else if (s == 13) {
      stageB128(MtB, DIN, PM0, tid);
      stageB128(MtB + (size_t)DOUT * DIN, DIN, PM1, tid);
      WAITVM(4);               // drains tile 15; M0,M1 in flight
    } else if (s == 14) {
      stageB128(MtB + (size_t)2 * DOUT * DIN, DIN, PM2, tid);
      stageX320(Xa, Xs0, tid);
      WAITVM(0);               // phase boundary: drain M0..M2 + X0
    }                           // s == 15: no stage, nothing outstanding
    SBAR();
  }

  // ---- phase 2: AR conv, 8 slices x 10 taps ----
  for (int k0 = 0; k0 < 8; ++k0) {
    int kc = k0 * 64;
    const short* xs = (k0 & 1) ? Xs1 : Xs0;
    short*       xn = (k0 & 1) ? Xs0 : Xs1;
    const short* q0 = (k0 % 3 == 0) ? PM0 : (k0 % 3 == 1) ? PM1 : PM2;
    const short* q1 = (k0 % 3 == 0) ? PM1 : (k0 % 3 == 1) ? PM2 : PM0;
    const short* q2 = (k0 % 3 == 0) ? PM2 : (k0 % 3 == 1) ? PM0 : PM1;
    #pragma unroll
    for (int j = 0; j < KX; ++j) {
      __builtin_amdgcn_s_setprio(1);
      mfma_frags(fr[j & 1], acc);
      bool do_read = (j < 9) || (k0 < 7);
      if (j < 9) {
        const short* mn = ((j + 1) % 3 == 0) ? q0 : ((j + 1) % 3 == 1) ? q1 : q2;
        read_frags(fr[(j + 1) & 1], xs, 15 - j, mn, lane, wm, wn);
      } else if (k0 < 7) {
        read_frags(fr[0], xn, 16, q1, lane, wm, wn);   // next slice tap 0
      }
      if (do_read) sgb_interleave();
      __builtin_amdgcn_s_setprio(0);
      LGKM0();
      SBAR();
      // stage M(j+3)
      if (j + 3 <= 9) {
        short* mw = (j % 3 == 0) ? (short*)q0 : (j % 3 == 1) ? (short*)q1 : (short*)q2;
        stageB128(MtB + (size_t)(j + 3) * DOUT * DIN + kc, DIN, mw, tid);
      } else if (k0 < 7) {
        short* mw = (j % 3 == 0) ? (short*)q0 : (j % 3 == 1) ? (short*)q1 : (short*)q2;
        stageB128(MtB + (size_t)(j - 7) * DOUT * DIN + kc + 64, DIN, mw, tid);
      }
      if (j == 1 && k0 < 7) stageX320(Xa + kc + 64, xn, tid);
      if (j == 1 || j == 2) {
        if (k0 < 7) { WAITVM(7); } else { WAITVM(2); }
      } else if (j >= 7) {
        if (k0 == 7) { WAITVM(0); } else { WAITVM(2); }
      } else {
        WAITVM(2);
      }
      SBAR();
    }
  }

  #pragma unroll
  for (int mi = 0; mi < 4; ++mi)
    #pragma unroll
    for (int ni = 0; ni < 4; ++ni)
      #pragma unroll
      for (int r = 0; r < 4; ++r) {
        long row = r0 + wm * 64 + mi * 16 + (lane >> 4) * 4 + r;
        int  col = c0 + wn * 64 + ni * 16 + (lane & 15);
        out[(size_t)row * DOUT + col] = acc[mi][ni][r];
      }
}

// ================= launch =================
extern "C" void kernel_launch(void* const* d_in, const int* in_sizes, int n_in,
                              void* d_out, int out_size, void* d_ws, size_t ws_size,
                              hipStream_t stream) {
  (void)in_sizes; (void)n_in; (void)out_size; (void)ws_size;
  const float* x  = (const float*)d_in[0];
  const float* h0 = (const float*)d_in[1];
  const float* A  = (const float*)d_in[2];
  const float* B  = (const float*)d_in[3];
  const float* C  = (const float*)d_in[4];
  const float* M  = (const float*)d_in[5];
  float* out = (float*)d_out;
  char* ws = (char*)d_ws;

  short* Xp  = (short*)(ws + OFF_XP);
  short* uB  = (short*)(ws + OFF_UB);
  short* hsb = (short*)(ws + OFF_HS);
  short* Bt  = (short*)(ws + OFF_BT);
  short* Ct  = (short*)(ws + OFF_CT);
  short* Mt  = (short*)(ws + OFF_MT);
  // scan scratch inside d_out (fully overwritten by k_gemm_out afterwards)
  float* E   = out;                    // B_SZ*NC*SDIM f32 = 1 MiB

  k_prep1<<<2560, 256, 0, stream>>>(x, B, Xp, Bt);
  k_gemm_uB<<<512, 512, 0, stream>>>(Xp, Bt, uB, A, E);
  k_scan_h<<<1792, 256, 0, stream>>>(uB, A, h0, E, hsb, C, M, Ct, Mt);
  k_gemm_out<<<256, 512, 0, stream>>>(hsb, Xp, Ct, Mt, out);
}